// Round 8
// baseline (173.342 us; speedup 1.0000x reference)
//
#include <hip/hip_runtime.h>
#include <math.h>

// Problem constants
#define BB 4
#define CC 64
#define HH 64
#define WW 64
#define HWP 4096            // H*W
#define NPTS 4096           // sample points per batch
#define LDP 72              // padded LDS row stride (bf16 elems)
constexpr float K_EPS   = 1e-5f;
constexpr float K_OFR   = 4.0f;
// Q is pre-scaled by 0.125 * log2(e) so logits feed exp2 directly.
constexpr float K_QSCALE = 0.18033688011112042f;

// Workspace layout (float offsets), NS in {8,4,2} chosen from ws_size.
//  OP [NS][B][M][C] at 0                    NS*1048576 fl
//  QB (bf16, 1048576 elems = 524288 fl) at NS*1048576
//  KB (bf16) at NS*1048576 + 524288
//  VB (bf16) at NS*1048576 + 1048576
//  DP [NS][B][M] (NS*16384 fl) at NS*1048576 + 1572864

typedef short frag8 __attribute__((ext_vector_type(8)));   // 8 bf16 (4 VGPRs)
typedef float f32x4 __attribute__((ext_vector_type(4)));

static __device__ inline unsigned short f2bf(float f) {
  unsigned int u = __builtin_bit_cast(unsigned int, f);
  unsigned int r = (u + 0x7fffu + ((u >> 16) & 1u)) >> 16;
  return (unsigned short)r;
}

#if defined(__has_builtin)
#if __has_builtin(__builtin_amdgcn_cvt_pk_bf16_f32)
#define HAVE_CVT_PK_BF16 1
#endif
#if __has_builtin(__builtin_amdgcn_exp2f)
#define EXP2F(x) __builtin_amdgcn_exp2f(x)
#endif
#endif
#ifndef EXP2F
#define EXP2F(x) exp2f(x)
#endif

// pack two floats to packed bf16 (RNE both paths)
static __device__ inline int pack2bf(float a, float b) {
#ifdef HAVE_CVT_PK_BF16
  auto r = __builtin_amdgcn_cvt_pk_bf16_f32(a, b);
  return __builtin_bit_cast(int, r);
#else
  return (int)f2bf(a) | ((int)f2bf(b) << 16);
#endif
}

// Abramowitz-Stegun 7.1.26 erf, |err| <= 1.5e-7 (plenty below harness tol)
static __device__ inline float erf_fast(float z) {
  float s = (z < 0.f) ? -1.f : 1.f;
  float a = fabsf(z);
  float t = 1.f / fmaf(0.3275911f, a, 1.f);
  float p = t * fmaf(t, fmaf(t, fmaf(t, fmaf(t, 1.061405429f, -1.453152027f),
                                     1.421413741f), -0.284496736f), 0.254829592f);
  float e = EXP2F(-a * a * 1.4426950408889634f);
  return s * (1.f - p * e);
}

// ---------------------------------------------------------------------------
// Kernel 1 (fully fused pre-stage): per block = one image row (b,y), 1024 thr
// = 64 px x 16 channel-groups of 4.
//   phase 0: stage wq (16 KB) + prompt rows y-1..y+1 all 64 ch (48 KB)
//   phase 1: q = conv1x1 for 3 rows -> regs (3x redundant halo compute)
//   phase 2: q -> LDS (over prompt region); qb (bf16, scaled) for row y
//   phase 3: depthwise 3x3 (LDS) + bias
//   phase 4: LN -> GELU(fast erf) -> offset proj -> tanh -> coords
//   phase 5: stage wk/wv over q region; bilinear-sample kv -> xs
//   phase 6: K/V projection -> kb, vb
// fp32 q NEVER touches global memory.
// ---------------------------------------------------------------------------
__global__ __launch_bounds__(1024) void k_prep(
    const float* __restrict__ prompt, const float* __restrict__ wq,
    const float* __restrict__ bq,
    const float* __restrict__ dw_w, const float* __restrict__ dw_b,
    const float* __restrict__ ln_w, const float* __restrict__ ln_b,
    const float* __restrict__ off_w, const float* __restrict__ kv,
    const float* __restrict__ wk, const float* __restrict__ bk,
    const float* __restrict__ wv, const float* __restrict__ bv,
    unsigned short* __restrict__ qb, unsigned short* __restrict__ kb,
    unsigned short* __restrict__ vb) {
  __shared__ float buf[16384];   // 64 KB, phase-aliased
  float* w_s = buf;              // [0..4095]: wq (ph0-1); red0=[0..1023],
                                 // red1=[1024..2047], coords=[2048..2175] (ph4+)
  float* pq  = buf + 4096;       // [12288]: prompt/q [c][3][64] (ph0-3);
                                 // wk=[+0..4095], wv=[+4096..8191], xs=[+8192..12287] (ph5+)
  int tid = threadIdx.x;
  int x = tid & 63, og = tid >> 6;         // og 0..15
  int by = blockIdx.x; int b = by >> 6, y = by & 63;

  // ---- phase 0 ----
#pragma unroll
  for (int i = 0; i < 4; ++i) w_s[i * 1024 + tid] = wq[i * 1024 + tid];
#pragma unroll
  for (int i = 0; i < 12; ++i) {
    int idx = i * 1024 + tid;
    int j = idx >> 6, xx = idx & 63;
    int c = j / 3, r = j - c * 3;
    int ry = min(max(y + r - 1, 0), HH - 1);
    pq[idx] = prompt[(size_t)(b * CC + c) * HWP + ry * WW + xx];
  }
  __syncthreads();

  // ---- phase 1: conv1x1 for 3 rows (own pixel, 4 out-ch) ----
  float qreg[3][4];
#pragma unroll
  for (int r = 0; r < 3; ++r)
#pragma unroll
    for (int oo = 0; oo < 4; ++oo) qreg[r][oo] = bq[og * 4 + oo];
  for (int cg = 0; cg < 16; ++cg) {
    float4 w4[4];
#pragma unroll
    for (int oo = 0; oo < 4; ++oo)
      w4[oo] = *(const float4*)&w_s[(og * 4 + oo) * 64 + cg * 4];
#pragma unroll
    for (int r = 0; r < 3; ++r) {
      float p0 = pq[(cg * 4 + 0) * 192 + r * 64 + x];
      float p1 = pq[(cg * 4 + 1) * 192 + r * 64 + x];
      float p2 = pq[(cg * 4 + 2) * 192 + r * 64 + x];
      float p3 = pq[(cg * 4 + 3) * 192 + r * 64 + x];
#pragma unroll
      for (int oo = 0; oo < 4; ++oo)
        qreg[r][oo] = fmaf(w4[oo].x, p0, fmaf(w4[oo].y, p1,
                      fmaf(w4[oo].z, p2, fmaf(w4[oo].w, p3, qreg[r][oo]))));
    }
  }
  __syncthreads();   // all prompt reads done

  // ---- phase 2: q -> LDS (over prompt region); qb write for row y ----
#pragma unroll
  for (int r = 0; r < 3; ++r)
#pragma unroll
    for (int oo = 0; oo < 4; ++oo)
      pq[(og * 4 + oo) * 192 + r * 64 + x] = qreg[r][oo];
  {
    int2 qq;
    qq.x = pack2bf(qreg[1][0] * K_QSCALE, qreg[1][1] * K_QSCALE);
    qq.y = pack2bf(qreg[1][2] * K_QSCALE, qreg[1][3] * K_QSCALE);
    *(int2*)&qb[(size_t)(b * HWP + y * WW + x) * CC + og * 4] = qq;
  }
  __syncthreads();   // q visible

  // ---- phase 3: depthwise 3x3 + bias ----
  float t[4];
#pragma unroll
  for (int i = 0; i < 4; ++i) {
    int c = og * 4 + i;
    float acc = dw_b[c];
#pragma unroll
    for (int ky = 0; ky < 3; ++ky) {
      int yy = y + ky - 1;
      bool yok = (yy >= 0) && (yy < HH);
#pragma unroll
      for (int kx = 0; kx < 3; ++kx) {
        int xx = x + kx - 1;
        bool ok = yok && (xx >= 0) && (xx < WW);
        int xc = min(max(xx, 0), WW - 1);
        float v = ok ? pq[c * 192 + ky * 64 + xc] : 0.f;
        acc = fmaf(dw_w[c * 9 + ky * 3 + kx], v, acc);
      }
    }
    t[i] = acc;
  }
  __syncthreads();   // all q reads done -> pq region free

  // ---- phase 5a: stage wk/wv over freed q region (overlaps LN phases) ----
  float* wk_s = pq;
  float* wv_s = pq + 4096;
  float* xs_s = pq + 8192;
#pragma unroll
  for (int i = 0; i < 4; ++i) {
    wk_s[i * 1024 + tid] = wk[i * 1024 + tid];
    wv_s[i * 1024 + tid] = wv[i * 1024 + tid];
  }

  // ---- phase 4: LN -> GELU -> offset proj -> coords ----
  float* red0 = w_s;           // [16][64]
  float* red1 = w_s + 1024;    // [16][64]
  float s1 = 0.f, s2 = 0.f;
#pragma unroll
  for (int i = 0; i < 4; ++i) { s1 += t[i]; s2 += t[i] * t[i]; }
  red0[og * 64 + x] = s1;
  red1[og * 64 + x] = s2;
  __syncthreads();
  float mu = 0.f, ms = 0.f;
#pragma unroll
  for (int g = 0; g < 16; ++g) { mu += red0[g * 64 + x]; ms += red1[g * 64 + x]; }
  mu *= (1.f / 64.f); ms *= (1.f / 64.f);
  float rstd = rsqrtf(ms - mu * mu + K_EPS);

  float oy = 0.f, ox = 0.f;
#pragma unroll
  for (int i = 0; i < 4; ++i) {
    int c = og * 4 + i;
    float g = (t[i] - mu) * rstd * ln_w[c] + ln_b[c];
    g = 0.5f * g * (1.f + erf_fast(g * 0.70710678118654752f));
    oy = fmaf(off_w[c], g, oy);
    ox = fmaf(off_w[CC + c], g, ox);
  }
  __syncthreads();   // mu/ms reads done
  red0[og * 64 + x] = oy;
  red1[og * 64 + x] = ox;
  __syncthreads();
  if (og == 0) {
    float osy = 0.f, osx = 0.f;
#pragma unroll
    for (int g = 0; g < 16; ++g) { osy += red0[g * 64 + x]; osx += red1[g * 64 + x]; }
    osy = tanhf(osy) * (K_OFR / (HH - 1));
    osx = tanhf(osx) * (K_OFR / (WW - 1));
    float ry = (y + 0.5f) * (2.f / 63.f) - 1.f;
    float rx = (x + 0.5f) * (2.f / 63.f) - 1.f;
    w_s[2048 + x] = (osx + rx + 1.f) * 0.5f * (WW - 1);   // gx
    w_s[2112 + x] = (osy + ry + 1.f) * 0.5f * (HH - 1);   // gy
  }
  __syncthreads();

  // ---- phase 5b: bilinear sample -> xs ----
  int n = x;
  int n0 = y * 64;
  float gx = w_s[2048 + n], gy = w_s[2112 + n];
  float x0f = floorf(gx), y0f = floorf(gy);
  float wx = gx - x0f, wy = gy - y0f;
  int x0 = (int)x0f, y0 = (int)y0f;
  int x1 = x0 + 1, y1 = y0 + 1;
  float m00 = (x0 >= 0 && x0 < WW && y0 >= 0 && y0 < HH) ? 1.f : 0.f;
  float m01 = (x1 >= 0 && x1 < WW && y0 >= 0 && y0 < HH) ? 1.f : 0.f;
  float m10 = (x0 >= 0 && x0 < WW && y1 >= 0 && y1 < HH) ? 1.f : 0.f;
  float m11 = (x1 >= 0 && x1 < WW && y1 >= 0 && y1 < HH) ? 1.f : 0.f;
  int x0c = min(max(x0, 0), WW - 1), x1c = min(max(x1, 0), WW - 1);
  int y0c = min(max(y0, 0), HH - 1), y1c = min(max(y1, 0), HH - 1);
  int i00 = y0c * WW + x0c, i01 = y0c * WW + x1c;
  int i10 = y1c * WW + x0c, i11 = y1c * WW + x1c;
  float w00 = m00 * (1.f - wx) * (1.f - wy);
  float w01 = m01 * wx * (1.f - wy);
  float w10 = m10 * (1.f - wx) * wy;
  float w11 = m11 * wx * wy;

  const float* base = kv + (size_t)b * CC * HWP;
#pragma unroll
  for (int i = 0; i < 4; ++i) {
    int c = og * 4 + i;
    const float* pc = base + (size_t)c * HWP;
    xs_s[c * 64 + n] = w00 * pc[i00] + w01 * pc[i01] + w10 * pc[i10] + w11 * pc[i11];
  }
  __syncthreads();

  // ---- phase 6: K/V projection ----
  float ak[4], av[4];
#pragma unroll
  for (int oo = 0; oo < 4; ++oo) { ak[oo] = bk[og * 4 + oo]; av[oo] = bv[og * 4 + oo]; }
  for (int cg2 = 0; cg2 < 16; ++cg2) {
    float p0 = xs_s[(cg2 * 4 + 0) * 64 + n];
    float p1 = xs_s[(cg2 * 4 + 1) * 64 + n];
    float p2 = xs_s[(cg2 * 4 + 2) * 64 + n];
    float p3 = xs_s[(cg2 * 4 + 3) * 64 + n];
#pragma unroll
    for (int oo = 0; oo < 4; ++oo) {
      int o = og * 4 + oo;
      const float4 k4 = *(const float4*)&wk_s[o * 64 + cg2 * 4];
      const float4 v4 = *(const float4*)&wv_s[o * 64 + cg2 * 4];
      ak[oo] = fmaf(k4.x, p0, fmaf(k4.y, p1, fmaf(k4.z, p2, fmaf(k4.w, p3, ak[oo]))));
      av[oo] = fmaf(v4.x, p0, fmaf(v4.y, p1, fmaf(v4.z, p2, fmaf(v4.w, p3, av[oo]))));
    }
  }
  int2 kk;
  kk.x = pack2bf(ak[0], ak[1]);
  kk.y = pack2bf(ak[2], ak[3]);
  *(int2*)&kb[(size_t)(b * NPTS + n0 + n) * CC + og * 4] = kk;
#pragma unroll
  for (int oo = 0; oo < 4; ++oo) {
    int o = og * 4 + oo;
    vb[(size_t)(b * CC + o) * NPTS + n0 + n] = f2bf(av[oo]);
  }
}

// ---------------------------------------------------------------------------
// Kernel 2: bf16 MFMA flash attention (unchanged from round 7 — verified).
// ---------------------------------------------------------------------------
__global__ __launch_bounds__(256) void k_attn(
    const unsigned short* __restrict__ qb, const unsigned short* __restrict__ kb,
    const unsigned short* __restrict__ vb, float* __restrict__ opart,
    float* __restrict__ dpart, int ns_shift) {
  __shared__ short qp_s[64 * LDP];   // Q tile, then P tile (aliased)
  __shared__ short k_s[64 * LDP];
  __shared__ short v_s[64 * LDP];

  int tid = threadIdx.x;
  int w = tid >> 6, lane = tid & 63, quad = lane >> 4, l16 = lane & 15;
  int blk = blockIdx.x;              // mt * (BB<<ns_shift) + (b<<ns_shift) + ns
  int pair = blk & ((BB << ns_shift) - 1);
  int mt = blk >> (2 + ns_shift);
  int ns = pair & ((1 << ns_shift) - 1);
  int b = pair >> ns_shift;
  int m0 = mt * 64;

  const unsigned short* qbb = qb + (size_t)b * HWP * CC;
  const unsigned short* kbb = kb + (size_t)b * NPTS * CC;
  const unsigned short* vbb = vb + (size_t)b * CC * NPTS;

#pragma unroll
  for (int pass = 0; pass < 2; ++pass) {
    int idx = pass * 256 + tid;
    int row = idx >> 3, part = idx & 7;
    uint4 d = *(const uint4*)(qbb + (size_t)(m0 + row) * CC + part * 8);
    *(uint4*)&qp_s[row * LDP + part * 8] = d;
  }
  __syncthreads();
  frag8 a_frag[2];
#pragma unroll
  for (int kc = 0; kc < 2; ++kc)
    a_frag[kc] = *(const frag8*)&qp_s[(w * 16 + l16) * LDP + kc * 32 + quad * 8];

  frag8 ones;
#pragma unroll
  for (int i = 0; i < 8; ++i) ones[i] = (short)0x3F80;   // bf16 1.0

  f32x4 o_acc[4];
  f32x4 d4;
  const f32x4 zz = {0.f, 0.f, 0.f, 0.f};
#pragma unroll
  for (int i = 0; i < 4; ++i) o_acc[i] = zz;
  d4 = zz;

  int niters = (NPTS / 64) >> ns_shift;
  int nbase = ns * niters * 64;
  for (int it = 0; it < niters; ++it) {
    int n0 = nbase + it * 64;
    __syncthreads();
#pragma unroll
    for (int pass = 0; pass < 2; ++pass) {
      int idx = pass * 256 + tid;
      int row = idx >> 3, part = idx & 7;
      uint4 dk = *(const uint4*)(kbb + (size_t)(n0 + row) * CC + part * 8);
      uint4 dv = *(const uint4*)(vbb + (size_t)row * NPTS + n0 + part * 8);
      *(uint4*)&k_s[row * LDP + part * 8] = dk;
      *(uint4*)&v_s[row * LDP + part * 8] = dv;
    }
    __syncthreads();

    f32x4 sT[4];
#pragma unroll
    for (int t = 0; t < 4; ++t) {
      frag8 kf = *(const frag8*)&k_s[(t * 16 + l16) * LDP + quad * 8];
      sT[t] = __builtin_amdgcn_mfma_f32_16x16x32_bf16(kf, a_frag[0], zz, 0, 0, 0);
    }
#pragma unroll
    for (int t = 0; t < 4; ++t) {
      frag8 kf = *(const frag8*)&k_s[(t * 16 + l16) * LDP + 32 + quad * 8];
      sT[t] = __builtin_amdgcn_mfma_f32_16x16x32_bf16(kf, a_frag[1], sT[t], 0, 0, 0);
    }
#pragma unroll
    for (int t = 0; t < 4; ++t) {
      int base_sh = (w * 16 + l16) * LDP + t * 16 + quad * 4;  // even
      int p01 = pack2bf(EXP2F(sT[t][0]), EXP2F(sT[t][1]));
      int p23 = pack2bf(EXP2F(sT[t][2]), EXP2F(sT[t][3]));
      *(int*)&qp_s[base_sh]     = p01;
      *(int*)&qp_s[base_sh + 2] = p23;
    }
#pragma unroll
    for (int kc = 0; kc < 2; ++kc) {
      frag8 bp = *(const frag8*)&qp_s[(w * 16 + l16) * LDP + kc * 32 + quad * 8];
      d4 = __builtin_amdgcn_mfma_f32_16x16x32_bf16(ones, bp, d4, 0, 0, 0);
#pragma unroll
      for (int ct = 0; ct < 4; ++ct) {
        frag8 av = *(const frag8*)&v_s[(ct * 16 + l16) * LDP + kc * 32 + quad * 8];
        o_acc[ct] = __builtin_amdgcn_mfma_f32_16x16x32_bf16(av, bp, o_acc[ct], 0, 0, 0);
      }
    }
  }

  float* op = opart + (size_t)((ns * BB + b) * HWP + m0 + w * 16 + l16) * CC;
#pragma unroll
  for (int ct = 0; ct < 4; ++ct) {
    float4 o4;
    o4.x = o_acc[ct][0]; o4.y = o_acc[ct][1]; o4.z = o_acc[ct][2]; o4.w = o_acc[ct][3];
    *(float4*)&op[ct * 16 + quad * 4] = o4;
  }
  if (lane < 16)
    dpart[(ns * BB + b) * HWP + m0 + w * 16 + lane] = d4[0];
}

// ---------------------------------------------------------------------------
// Kernel 3: combine NS partials, normalize, project with wo (unchanged r7).
// ---------------------------------------------------------------------------
__global__ __launch_bounds__(256) void k_out(
    const float* __restrict__ opart, const float* __restrict__ dpart,
    const float* __restrict__ wo, const float* __restrict__ bo,
    float* __restrict__ out, int NS) {
  __shared__ float wo_s[CC * CC];
  __shared__ float t_s[32 * 65];    // [m][c] padded
  int tid = threadIdx.x;
  int blk = blockIdx.x;             // b*128 + mt
  int b = blk >> 7, mt = blk & 127, m0 = mt * 32;
  for (int i = tid; i < CC * CC; i += 256) wo_s[i] = wo[i];

#pragma unroll
  for (int it = 0; it < 8; ++it) {
    int idx = it * 256 + tid;
    int m = idx >> 6, c = idx & 63;
    float o = 0.f, d = 0.f;
    for (int s = 0; s < NS; ++s) {
      o += opart[(size_t)((s * BB + b) * HWP + m0 + m) * CC + c];
      d += dpart[(s * BB + b) * HWP + m0 + m];
    }
    t_s[m * 65 + c] = o / d;
  }
  __syncthreads();
  int ml = tid & 31, og = tid >> 5;  // og 0..7
  for (int oo = 0; oo < 8; ++oo) {
    int o = og * 8 + oo;
    float acc = bo[o];
#pragma unroll
    for (int c = 0; c < 64; ++c) acc = fmaf(wo_s[o * CC + c], t_s[ml * 65 + c], acc);
    out[(size_t)(b * CC + o) * HWP + m0 + ml] = acc;
  }
}

// ---------------------------------------------------------------------------
extern "C" void kernel_launch(void* const* d_in, const int* in_sizes, int n_in,
                              void* d_out, int out_size, void* d_ws, size_t ws_size,
                              hipStream_t stream) {
  const float* prompt = (const float*)d_in[0];
  const float* kv     = (const float*)d_in[1];
  const float* wq     = (const float*)d_in[2];
  const float* bq     = (const float*)d_in[3];
  const float* wk     = (const float*)d_in[4];
  const float* bk     = (const float*)d_in[5];
  const float* wv     = (const float*)d_in[6];
  const float* bv     = (const float*)d_in[7];
  const float* wo     = (const float*)d_in[8];
  const float* bo     = (const float*)d_in[9];
  const float* dw_w   = (const float*)d_in[10];
  const float* dw_b   = (const float*)d_in[11];
  const float* ln_w   = (const float*)d_in[12];
  const float* ln_b   = (const float*)d_in[13];
  const float* off_w  = (const float*)d_in[14];
  float* out = (float*)d_out;
  float* ws  = (float*)d_ws;

  // NS gating on workspace size (deterministic per run — ws_size is fixed).
  auto need = [](int ns) {
    return (size_t)((size_t)ns * 1048576 + 3 * 524288 + (size_t)ns * 16384) * sizeof(float);
  };
  int NS, ns_shift;
  if      (ws_size >= need(8)) { NS = 8; ns_shift = 3; }
  else if (ws_size >= need(4)) { NS = 4; ns_shift = 2; }
  else                         { NS = 2; ns_shift = 1; }

  float* opart          = ws;                         // [NS][B][M][C]
  unsigned short* qb    = (unsigned short*)(ws + (size_t)NS * 1048576);
  unsigned short* kb    = (unsigned short*)(ws + (size_t)NS * 1048576 + 524288);
  unsigned short* vb    = (unsigned short*)(ws + (size_t)NS * 1048576 + 2 * 524288);
  float* dpart          = ws + (size_t)NS * 1048576 + 3 * 524288;

  hipLaunchKernelGGL(k_prep, dim3(BB * HH), dim3(1024), 0, stream,
                     prompt, wq, bq, dw_w, dw_b, ln_w, ln_b, off_w,
                     kv, wk, bk, wv, bv, qb, kb, vb);
  hipLaunchKernelGGL(k_attn, dim3(BB * NS * 64), dim3(256), 0, stream,
                     qb, kb, vb, opart, dpart, ns_shift);
  hipLaunchKernelGGL(k_out, dim3(BB * 128), dim3(256), 0, stream,
                     opart, dpart, wo, bo, out, NS);
}

// Round 9
// 170.023 us; speedup vs baseline: 1.0195x; 1.0195x over previous
//
#include <hip/hip_runtime.h>
#include <math.h>

// Problem constants
#define BB 4
#define CC 64
#define HH 64
#define WW 64
#define HWP 4096            // H*W
#define NPTS 4096           // sample points per batch
#define LDP 72              // padded LDS row stride (bf16 elems)
constexpr float K_EPS   = 1e-5f;
constexpr float K_OFR   = 4.0f;
// Q is pre-scaled by 0.125 * log2(e) so logits feed exp2 directly.
constexpr float K_QSCALE = 0.18033688011112042f;

// Workspace layout (float offsets), NS in {8,4,2} chosen from ws_size.
//  OP [NS][B][M][C] at 0 (aliases QF: qf dead before k_attn writes) NS*1048576 fl
//  QF [B][C][HW]    at 0                                            1048576 fl
//  QB (bf16, 1048576 elems = 524288 fl) at NS*1048576
//  KB (bf16) at NS*1048576 + 524288
//  VB (bf16) at NS*1048576 + 1048576
//  DP [NS][B][M] (NS*16384 fl) at NS*1048576 + 1572864

typedef short frag8 __attribute__((ext_vector_type(8)));   // 8 bf16 (4 VGPRs)
typedef float f32x4 __attribute__((ext_vector_type(4)));

static __device__ inline unsigned short f2bf(float f) {
  unsigned int u = __builtin_bit_cast(unsigned int, f);
  unsigned int r = (u + 0x7fffu + ((u >> 16) & 1u)) >> 16;
  return (unsigned short)r;
}

#if defined(__has_builtin)
#if __has_builtin(__builtin_amdgcn_cvt_pk_bf16_f32)
#define HAVE_CVT_PK_BF16 1
#endif
#if __has_builtin(__builtin_amdgcn_exp2f)
#define EXP2F(x) __builtin_amdgcn_exp2f(x)
#endif
#endif
#ifndef EXP2F
#define EXP2F(x) exp2f(x)
#endif

// pack two floats to packed bf16 (RNE both paths)
static __device__ inline int pack2bf(float a, float b) {
#ifdef HAVE_CVT_PK_BF16
  auto r = __builtin_amdgcn_cvt_pk_bf16_f32(a, b);
  return __builtin_bit_cast(int, r);
#else
  return (int)f2bf(a) | ((int)f2bf(b) << 16);
#endif
}

// Abramowitz-Stegun 7.1.26 erf, |err| <= 1.5e-7
static __device__ inline float erf_fast(float z) {
  float s = (z < 0.f) ? -1.f : 1.f;
  float a = fabsf(z);
  float t = 1.f / fmaf(0.3275911f, a, 1.f);
  float p = t * fmaf(t, fmaf(t, fmaf(t, fmaf(t, 1.061405429f, -1.453152027f),
                                     1.421413741f), -0.284496736f), 0.254829592f);
  float e = EXP2F(-a * a * 1.4426950408889634f);
  return s * (1.f - p * e);
}

// ---------------------------------------------------------------------------
// Kernel 1: q = conv1x1(prompt, wq, bq); fp32 [B][C][HW] + bf16 scaled [B][M][C].
// Grid 256 x 1024 thr: 64 pixels x 16 o-groups of 4.  (r7-verified)
// ---------------------------------------------------------------------------
__global__ __launch_bounds__(1024) void k_qproj(
    const float* __restrict__ prompt, const float* __restrict__ wq,
    const float* __restrict__ bq, float* __restrict__ qf,
    unsigned short* __restrict__ qb) {
  __shared__ float w_s[64 * 64];
  __shared__ float p_s[64 * 64];           // [c][pix]
  __shared__ unsigned short t_s[64 * 68];  // [pix][c] pad 4
  int tid = threadIdx.x;
  int blk = blockIdx.x;                    // b*64 + row-tile
  int b = blk >> 6; int hw0 = (blk & 63) * 64;
#pragma unroll
  for (int i = 0; i < 4; ++i) w_s[i * 1024 + tid] = wq[i * 1024 + tid];
#pragma unroll
  for (int i = 0; i < 4; ++i) {
    int idx = i * 1024 + tid; int c = idx >> 6, pix = idx & 63;
    p_s[idx] = prompt[(size_t)(b * CC + c) * HWP + hw0 + pix];
  }
  __syncthreads();
  int x = tid & 63, og = tid >> 6;         // og 0..15
  float acc[4];
#pragma unroll
  for (int oo = 0; oo < 4; ++oo) acc[oo] = bq[og * 4 + oo];
  for (int cg = 0; cg < 16; ++cg) {
    float p0 = p_s[(cg * 4 + 0) * 64 + x];
    float p1 = p_s[(cg * 4 + 1) * 64 + x];
    float p2 = p_s[(cg * 4 + 2) * 64 + x];
    float p3 = p_s[(cg * 4 + 3) * 64 + x];
#pragma unroll
    for (int oo = 0; oo < 4; ++oo) {
      const float4 w4 = *(const float4*)&w_s[(og * 4 + oo) * 64 + cg * 4];
      acc[oo] = fmaf(w4.x, p0, fmaf(w4.y, p1, fmaf(w4.z, p2, fmaf(w4.w, p3, acc[oo]))));
    }
  }
#pragma unroll
  for (int oo = 0; oo < 4; ++oo) {
    int o = og * 4 + oo;
    qf[(size_t)(b * CC + o) * HWP + hw0 + x] = acc[oo];
    t_s[x * 68 + o] = f2bf(acc[oo] * K_QSCALE);
  }
  __syncthreads();
  {
    int pix = tid >> 4, c4 = tid & 15;
    ushort4 v = *(const ushort4*)&t_s[pix * 68 + c4 * 4];
    *(ushort4*)&qb[(size_t)(b * HWP + hw0 + pix) * CC + c4 * 4] = v;
  }
}

// ---------------------------------------------------------------------------
// Kernel 2 (fused): depthwise3x3(q)+bias -> LN -> GELU(fast erf) -> offset
// proj -> tanh -> coords -> bilinear-sample kv -> K/V projection.
// Grid B*H = 256 x 1024 thr: 64 px x 16 channel-groups of 4.  (r7 + erf_fast)
// ---------------------------------------------------------------------------
__global__ __launch_bounds__(1024) void k_off_sample(
    const float* __restrict__ q, const float* __restrict__ dw_w,
    const float* __restrict__ dw_b, const float* __restrict__ ln_w,
    const float* __restrict__ ln_b, const float* __restrict__ off_w,
    const float* __restrict__ kv,
    const float* __restrict__ wk, const float* __restrict__ bk,
    const float* __restrict__ wv, const float* __restrict__ bv,
    unsigned short* __restrict__ kb, unsigned short* __restrict__ vb) {
  __shared__ float wk_s[64 * 64];
  __shared__ float wv_s[64 * 64];
  __shared__ float xs_s[64 * 64];   // [c][n]
  __shared__ float red0[16][64];
  __shared__ float red1[16][64];

  int tid = threadIdx.x;
  int x = tid & 63;
  int cg = tid >> 6;                // 0..15
  int by = blockIdx.x;              // b*H + y
  int b = by >> 6;
  int y = by & 63;

#pragma unroll
  for (int i = 0; i < 4; ++i) {
    wk_s[i * 1024 + tid] = wk[i * 1024 + tid];
    wv_s[i * 1024 + tid] = wv[i * 1024 + tid];
  }

  // ---- phase 1: offsets ----
  float t[4];
#pragma unroll
  for (int i = 0; i < 4; ++i) {
    int c = cg * 4 + i;
    float acc = dw_b[c];
    const float* qc = q + (size_t)(b * CC + c) * HWP;
#pragma unroll
    for (int ky = 0; ky < 3; ++ky) {
      int yy = y + ky - 1;
      bool yok = (yy >= 0) && (yy < HH);
#pragma unroll
      for (int kx = 0; kx < 3; ++kx) {
        int xx = x + kx - 1;
        bool ok = yok && (xx >= 0) && (xx < WW);
        float v = ok ? qc[yy * WW + xx] : 0.f;
        acc = fmaf(dw_w[c * 9 + ky * 3 + kx], v, acc);
      }
    }
    t[i] = acc;
  }
  float s1 = 0.f, s2 = 0.f;
#pragma unroll
  for (int i = 0; i < 4; ++i) { s1 += t[i]; s2 += t[i] * t[i]; }
  red0[cg][x] = s1;
  red1[cg][x] = s2;
  __syncthreads();
  float mu = 0.f, ms = 0.f;
#pragma unroll
  for (int g = 0; g < 16; ++g) { mu += red0[g][x]; ms += red1[g][x]; }
  mu *= (1.f / 64.f); ms *= (1.f / 64.f);
  float rstd = rsqrtf(ms - mu * mu + K_EPS);

  float oy = 0.f, ox = 0.f;
#pragma unroll
  for (int i = 0; i < 4; ++i) {
    int c = cg * 4 + i;
    float g = (t[i] - mu) * rstd * ln_w[c] + ln_b[c];
    g = 0.5f * g * (1.f + erf_fast(g * 0.70710678118654752f));
    oy = fmaf(off_w[c], g, oy);
    ox = fmaf(off_w[CC + c], g, ox);
  }
  __syncthreads();
  red0[cg][x] = oy;
  red1[cg][x] = ox;
  __syncthreads();
  if (cg == 0) {
    float osy = 0.f, osx = 0.f;
#pragma unroll
    for (int g = 0; g < 16; ++g) { osy += red0[g][x]; osx += red1[g][x]; }
    osy = tanhf(osy) * (K_OFR / (HH - 1));
    osx = tanhf(osx) * (K_OFR / (WW - 1));
    float ry = (y + 0.5f) * (2.f / 63.f) - 1.f;
    float rx = (x + 0.5f) * (2.f / 63.f) - 1.f;
    red0[0][x] = (osx + rx + 1.f) * 0.5f * (WW - 1);   // gx
    red0[1][x] = (osy + ry + 1.f) * 0.5f * (HH - 1);   // gy
  }
  __syncthreads();

  // ---- phase 2: sample + K/V projection ----
  int n = x, og = cg;
  int n0 = y * 64;
  float gx = red0[0][n], gy = red0[1][n];
  float x0f = floorf(gx), y0f = floorf(gy);
  float wx = gx - x0f, wy = gy - y0f;
  int x0 = (int)x0f, y0 = (int)y0f;
  int x1 = x0 + 1, y1 = y0 + 1;
  float m00 = (x0 >= 0 && x0 < WW && y0 >= 0 && y0 < HH) ? 1.f : 0.f;
  float m01 = (x1 >= 0 && x1 < WW && y0 >= 0 && y0 < HH) ? 1.f : 0.f;
  float m10 = (x0 >= 0 && x0 < WW && y1 >= 0 && y1 < HH) ? 1.f : 0.f;
  float m11 = (x1 >= 0 && x1 < WW && y1 >= 0 && y1 < HH) ? 1.f : 0.f;
  int x0c = min(max(x0, 0), WW - 1), x1c = min(max(x1, 0), WW - 1);
  int y0c = min(max(y0, 0), HH - 1), y1c = min(max(y1, 0), HH - 1);
  int i00 = y0c * WW + x0c, i01 = y0c * WW + x1c;
  int i10 = y1c * WW + x0c, i11 = y1c * WW + x1c;
  float w00 = m00 * (1.f - wx) * (1.f - wy);
  float w01 = m01 * wx * (1.f - wy);
  float w10 = m10 * (1.f - wx) * wy;
  float w11 = m11 * wx * wy;

  const float* base = kv + (size_t)b * CC * HWP;
#pragma unroll
  for (int i = 0; i < 4; ++i) {
    int c = og * 4 + i;
    const float* pc = base + (size_t)c * HWP;
    xs_s[c * 64 + n] = w00 * pc[i00] + w01 * pc[i01] + w10 * pc[i10] + w11 * pc[i11];
  }
  __syncthreads();
  float ak[4], av[4];
#pragma unroll
  for (int oo = 0; oo < 4; ++oo) { ak[oo] = bk[og * 4 + oo]; av[oo] = bv[og * 4 + oo]; }
  for (int cg2 = 0; cg2 < 16; ++cg2) {
    float p0 = xs_s[(cg2 * 4 + 0) * 64 + n];
    float p1 = xs_s[(cg2 * 4 + 1) * 64 + n];
    float p2 = xs_s[(cg2 * 4 + 2) * 64 + n];
    float p3 = xs_s[(cg2 * 4 + 3) * 64 + n];
#pragma unroll
    for (int oo = 0; oo < 4; ++oo) {
      int o = og * 4 + oo;
      const float4 k4 = *(const float4*)&wk_s[o * 64 + cg2 * 4];
      const float4 v4 = *(const float4*)&wv_s[o * 64 + cg2 * 4];
      ak[oo] = fmaf(k4.x, p0, fmaf(k4.y, p1, fmaf(k4.z, p2, fmaf(k4.w, p3, ak[oo]))));
      av[oo] = fmaf(v4.x, p0, fmaf(v4.y, p1, fmaf(v4.z, p2, fmaf(v4.w, p3, av[oo]))));
    }
  }
  int2 kk;
  kk.x = pack2bf(ak[0], ak[1]);
  kk.y = pack2bf(ak[2], ak[3]);
  *(int2*)&kb[(size_t)(b * NPTS + n0 + n) * CC + og * 4] = kk;
#pragma unroll
  for (int oo = 0; oo < 4; ++oo) {
    int o = og * 4 + oo;
    vb[(size_t)(b * CC + o) * NPTS + n0 + n] = f2bf(av[oo]);
  }
}

// ---------------------------------------------------------------------------
// Kernel 3: bf16 MFMA flash attention, n-stripe GEMM1.
// Grid = 64 * (B*NS) blocks (mt in high bits for XCD L2 locality), 256 thr.
// All 64 Q rows hoisted to registers (8 frag8/lane, loop-invariant).
// GEMM1: wave w computes S^T rows n=w*16..+15 for ALL m: A = K[w-stripe]
// (2 LDS reads/iter), B = Q regs.  P[m][n] now cross-wave -> 3rd barrier.
// LDS frag reads/wave-iter: 2(K) + 2(P) + 8(V) = 12 (was 18).
// ---------------------------------------------------------------------------
__global__ __launch_bounds__(256) void k_attn(
    const unsigned short* __restrict__ qb, const unsigned short* __restrict__ kb,
    const unsigned short* __restrict__ vb, float* __restrict__ opart,
    float* __restrict__ dpart, int ns_shift) {
  __shared__ short qp_s[64 * LDP];   // Q tile, then P tile (aliased)
  __shared__ short k_s[64 * LDP];
  __shared__ short v_s[64 * LDP];

  int tid = threadIdx.x;
  int w = tid >> 6, lane = tid & 63, quad = lane >> 4, l16 = lane & 15;
  int blk = blockIdx.x;              // mt * (BB<<ns_shift) + (b<<ns_shift) + ns
  int pair = blk & ((BB << ns_shift) - 1);
  int mtile = blk >> (2 + ns_shift);
  int ns = pair & ((1 << ns_shift) - 1);
  int b = pair >> ns_shift;
  int m0 = mtile * 64;

  const unsigned short* qbb = qb + (size_t)b * HWP * CC;
  const unsigned short* kbb = kb + (size_t)b * NPTS * CC;
  const unsigned short* vbb = vb + (size_t)b * CC * NPTS;

  // stage Q tile [m][c] (8 KB)
#pragma unroll
  for (int pass = 0; pass < 2; ++pass) {
    int idx = pass * 256 + tid;
    int row = idx >> 3, part = idx & 7;
    uint4 d = *(const uint4*)(qbb + (size_t)(m0 + row) * CC + part * 8);
    *(uint4*)&qp_s[row * LDP + part * 8] = d;
  }
  __syncthreads();
  // hoist ALL 64 Q rows as B-operand frags: qfr[mt][kc], loop-invariant
  frag8 qfr[4][2];
#pragma unroll
  for (int mt = 0; mt < 4; ++mt)
#pragma unroll
    for (int kc = 0; kc < 2; ++kc)
      qfr[mt][kc] = *(const frag8*)&qp_s[(mt * 16 + l16) * LDP + kc * 32 + quad * 8];

  frag8 ones;
#pragma unroll
  for (int i = 0; i < 8; ++i) ones[i] = (short)0x3F80;   // bf16 1.0

  f32x4 o_acc[4];
  f32x4 d4;
  const f32x4 zz = {0.f, 0.f, 0.f, 0.f};
#pragma unroll
  for (int i = 0; i < 4; ++i) o_acc[i] = zz;
  d4 = zz;

  int niters = (NPTS / 64) >> ns_shift;
  int nbase = ns * niters * 64;
  for (int it = 0; it < niters; ++it) {
    int n0 = nbase + it * 64;
    __syncthreads();   // (A) prev-iter GEMM2 reads (k_s/v_s/qp_s) done
#pragma unroll
    for (int pass = 0; pass < 2; ++pass) {
      int idx = pass * 256 + tid;
      int row = idx >> 3, part = idx & 7;
      uint4 dk = *(const uint4*)(kbb + (size_t)(n0 + row) * CC + part * 8);
      uint4 dv = *(const uint4*)(vbb + (size_t)row * NPTS + n0 + part * 8);
      *(uint4*)&k_s[row * LDP + part * 8] = dk;
      *(uint4*)&v_s[row * LDP + part * 8] = dv;
    }
    __syncthreads();   // (B) staging visible

    // GEMM1: wave-n-stripe.  A = K rows w*16+l16, B = Q regs.
    frag8 kf0 = *(const frag8*)&k_s[(w * 16 + l16) * LDP + quad * 8];
    frag8 kf1 = *(const frag8*)&k_s[(w * 16 + l16) * LDP + 32 + quad * 8];
    f32x4 sT[4];
#pragma unroll
    for (int mt = 0; mt < 4; ++mt)
      sT[mt] = __builtin_amdgcn_mfma_f32_16x16x32_bf16(kf0, qfr[mt][0], zz, 0, 0, 0);
#pragma unroll
    for (int mt = 0; mt < 4; ++mt)
      sT[mt] = __builtin_amdgcn_mfma_f32_16x16x32_bf16(kf1, qfr[mt][1], sT[mt], 0, 0, 0);
    // exp2 -> packed bf16 P[m][n]: rows mt*16+l16, column stripe w*16..
#pragma unroll
    for (int mt = 0; mt < 4; ++mt) {
      int base_sh = (mt * 16 + l16) * LDP + w * 16 + quad * 4;  // even
      *(int*)&qp_s[base_sh]     = pack2bf(EXP2F(sT[mt][0]), EXP2F(sT[mt][1]));
      *(int*)&qp_s[base_sh + 2] = pack2bf(EXP2F(sT[mt][2]), EXP2F(sT[mt][3]));
    }
    __syncthreads();   // (C) P visible cross-wave

    // GEMM2: O^T[c][m] += V[c][n] * P^T[n][m];  d += ones * P^T
#pragma unroll
    for (int kc = 0; kc < 2; ++kc) {
      frag8 bp = *(const frag8*)&qp_s[(w * 16 + l16) * LDP + kc * 32 + quad * 8];
      d4 = __builtin_amdgcn_mfma_f32_16x16x32_bf16(ones, bp, d4, 0, 0, 0);
#pragma unroll
      for (int ct = 0; ct < 4; ++ct) {
        frag8 av = *(const frag8*)&v_s[(ct * 16 + l16) * LDP + kc * 32 + quad * 8];
        o_acc[ct] = __builtin_amdgcn_mfma_f32_16x16x32_bf16(av, bp, o_acc[ct], 0, 0, 0);
      }
    }
  }

  // O^T lane layout: c = ct*16 + quad*4 + reg, m = w*16 + l16
  float* op = opart + (size_t)((ns * BB + b) * HWP + m0 + w * 16 + l16) * CC;
#pragma unroll
  for (int ct = 0; ct < 4; ++ct) {
    float4 o4;
    o4.x = o_acc[ct][0]; o4.y = o_acc[ct][1]; o4.z = o_acc[ct][2]; o4.w = o_acc[ct][3];
    *(float4*)&op[ct * 16 + quad * 4] = o4;
  }
  if (lane < 16)
    dpart[(ns * BB + b) * HWP + m0 + w * 16 + lane] = d4[0];
}

// ---------------------------------------------------------------------------
// Kernel 4: combine NS partials, normalize, project with wo (r7-verified).
// ---------------------------------------------------------------------------
__global__ __launch_bounds__(256) void k_out(
    const float* __restrict__ opart, const float* __restrict__ dpart,
    const float* __restrict__ wo, const float* __restrict__ bo,
    float* __restrict__ out, int NS) {
  __shared__ float wo_s[CC * CC];
  __shared__ float t_s[32 * 65];    // [m][c] padded
  int tid = threadIdx.x;
  int blk = blockIdx.x;             // b*128 + mt
  int b = blk >> 7, mt = blk & 127, m0 = mt * 32;
  for (int i = tid; i < CC * CC; i += 256) wo_s[i] = wo[i];

#pragma unroll
  for (int it = 0; it < 8; ++it) {
    int idx = it * 256 + tid;
    int m = idx >> 6, c = idx & 63;
    float o = 0.f, d = 0.f;
    for (int s = 0; s < NS; ++s) {
      o += opart[(size_t)((s * BB + b) * HWP + m0 + m) * CC + c];
      d += dpart[(s * BB + b) * HWP + m0 + m];
    }
    t_s[m * 65 + c] = o / d;
  }
  __syncthreads();
  int ml = tid & 31, og = tid >> 5;  // og 0..7
  for (int oo = 0; oo < 8; ++oo) {
    int o = og * 8 + oo;
    float acc = bo[o];
#pragma unroll
    for (int c = 0; c < 64; ++c) acc = fmaf(wo_s[o * CC + c], t_s[ml * 65 + c], acc);
    out[(size_t)(b * CC + o) * HWP + m0 + ml] = acc;
  }
}

// ---------------------------------------------------------------------------
extern "C" void kernel_launch(void* const* d_in, const int* in_sizes, int n_in,
                              void* d_out, int out_size, void* d_ws, size_t ws_size,
                              hipStream_t stream) {
  const float* prompt = (const float*)d_in[0];
  const float* kv     = (const float*)d_in[1];
  const float* wq     = (const float*)d_in[2];
  const float* bq     = (const float*)d_in[3];
  const float* wk     = (const float*)d_in[4];
  const float* bk     = (const float*)d_in[5];
  const float* wv     = (const float*)d_in[6];
  const float* bv     = (const float*)d_in[7];
  const float* wo     = (const float*)d_in[8];
  const float* bo     = (const float*)d_in[9];
  const float* dw_w   = (const float*)d_in[10];
  const float* dw_b   = (const float*)d_in[11];
  const float* ln_w   = (const float*)d_in[12];
  const float* ln_b   = (const float*)d_in[13];
  const float* off_w  = (const float*)d_in[14];
  float* out = (float*)d_out;
  float* ws  = (float*)d_ws;

  // NS gating on workspace size (deterministic per run — ws_size is fixed).
  auto need = [](int ns) {
    return (size_t)((size_t)ns * 1048576 + 3 * 524288 + (size_t)ns * 16384) * sizeof(float);
  };
  int NS, ns_shift;
  if      (ws_size >= need(8)) { NS = 8; ns_shift = 3; }
  else if (ws_size >= need(4)) { NS = 4; ns_shift = 2; }
  else                         { NS = 2; ns_shift = 1; }

  float* opart          = ws;                         // [NS][B][M][C], aliases qf
  float* qf             = ws;                         // [B][C][HW] (dead before k_attn)
  unsigned short* qb    = (unsigned short*)(ws + (size_t)NS * 1048576);
  unsigned short* kb    = (unsigned short*)(ws + (size_t)NS * 1048576 + 524288);
  unsigned short* vb    = (unsigned short*)(ws + (size_t)NS * 1048576 + 2 * 524288);
  float* dpart          = ws + (size_t)NS * 1048576 + 3 * 524288;

  hipLaunchKernelGGL(k_qproj, dim3(BB * 64), dim3(1024), 0, stream,
                     prompt, wq, bq, qf, qb);
  hipLaunchKernelGGL(k_off_sample, dim3(BB * HH), dim3(1024), 0, stream,
                     qf, dw_w, dw_b, ln_w, ln_b, off_w,
                     kv, wk, bk, wv, bv, kb, vb);
  hipLaunchKernelGGL(k_attn, dim3(BB * NS * 64), dim3(256), 0, stream,
                     qb, kb, vb, opart, dpart, ns_shift);
  hipLaunchKernelGGL(k_out, dim3(BB * 128), dim3(256), 0, stream,
                     opart, dpart, wo, bo, out, NS);
}

// Round 10
// 167.165 us; speedup vs baseline: 1.0370x; 1.0171x over previous
//
#include <hip/hip_runtime.h>
#include <math.h>

// Problem constants
#define BB 4
#define CC 64
#define HH 64
#define WW 64
#define HWP 4096            // H*W
#define NPTS 4096           // sample points per batch
#define LDP 72              // padded LDS row stride (bf16 elems)
constexpr float K_EPS   = 1e-5f;
constexpr float K_OFR   = 4.0f;
// Q is pre-scaled by 0.125 * log2(e) so logits feed exp2 directly.
constexpr float K_QSCALE = 0.18033688011112042f;

// Workspace layout (float offsets), NS in {8,4,2} chosen from ws_size.
//  OP [NS][B][M][C] at 0 (aliases QF: qf dead before k_attn writes) NS*1048576 fl
//  QF [B][C][HW]    at 0                                            1048576 fl
//  QB (bf16, 1048576 elems = 524288 fl) at NS*1048576
//  KB (bf16) at NS*1048576 + 524288
//  VB (bf16) at NS*1048576 + 1048576
//  DP [NS][B][M] (NS*16384 fl) at NS*1048576 + 1572864

typedef short frag8 __attribute__((ext_vector_type(8)));   // 8 bf16 (4 VGPRs)
typedef float f32x4 __attribute__((ext_vector_type(4)));

static __device__ inline unsigned short f2bf(float f) {
  unsigned int u = __builtin_bit_cast(unsigned int, f);
  unsigned int r = (u + 0x7fffu + ((u >> 16) & 1u)) >> 16;
  return (unsigned short)r;
}

#if defined(__has_builtin)
#if __has_builtin(__builtin_amdgcn_cvt_pk_bf16_f32)
#define HAVE_CVT_PK_BF16 1
#endif
#if __has_builtin(__builtin_amdgcn_exp2f)
#define EXP2F(x) __builtin_amdgcn_exp2f(x)
#endif
#endif
#ifndef EXP2F
#define EXP2F(x) exp2f(x)
#endif

// pack two floats to packed bf16 (RNE both paths)
static __device__ inline int pack2bf(float a, float b) {
#ifdef HAVE_CVT_PK_BF16
  auto r = __builtin_amdgcn_cvt_pk_bf16_f32(a, b);
  return __builtin_bit_cast(int, r);
#else
  return (int)f2bf(a) | ((int)f2bf(b) << 16);
#endif
}

// Abramowitz-Stegun 7.1.26 erf, |err| <= 1.5e-7
static __device__ inline float erf_fast(float z) {
  float s = (z < 0.f) ? -1.f : 1.f;
  float a = fabsf(z);
  float t = 1.f / fmaf(0.3275911f, a, 1.f);
  float p = t * fmaf(t, fmaf(t, fmaf(t, fmaf(t, 1.061405429f, -1.453152027f),
                                     1.421413741f), -0.284496736f), 0.254829592f);
  float e = EXP2F(-a * a * 1.4426950408889634f);
  return s * (1.f - p * e);
}

// ---------------------------------------------------------------------------
// Kernel 1: q = conv1x1(prompt, wq, bq); fp32 [B][C][HW] + bf16 scaled [B][M][C].
// Grid 256 x 1024 thr: 64 pixels x 16 o-groups of 4.  (r7-verified)
// ---------------------------------------------------------------------------
__global__ __launch_bounds__(1024) void k_qproj(
    const float* __restrict__ prompt, const float* __restrict__ wq,
    const float* __restrict__ bq, float* __restrict__ qf,
    unsigned short* __restrict__ qb) {
  __shared__ float w_s[64 * 64];
  __shared__ float p_s[64 * 64];           // [c][pix]
  __shared__ unsigned short t_s[64 * 68];  // [pix][c] pad 4
  int tid = threadIdx.x;
  int blk = blockIdx.x;                    // b*64 + row-tile
  int b = blk >> 6; int hw0 = (blk & 63) * 64;
#pragma unroll
  for (int i = 0; i < 4; ++i) w_s[i * 1024 + tid] = wq[i * 1024 + tid];
#pragma unroll
  for (int i = 0; i < 4; ++i) {
    int idx = i * 1024 + tid; int c = idx >> 6, pix = idx & 63;
    p_s[idx] = prompt[(size_t)(b * CC + c) * HWP + hw0 + pix];
  }
  __syncthreads();
  int x = tid & 63, og = tid >> 6;         // og 0..15
  float acc[4];
#pragma unroll
  for (int oo = 0; oo < 4; ++oo) acc[oo] = bq[og * 4 + oo];
  for (int cg = 0; cg < 16; ++cg) {
    float p0 = p_s[(cg * 4 + 0) * 64 + x];
    float p1 = p_s[(cg * 4 + 1) * 64 + x];
    float p2 = p_s[(cg * 4 + 2) * 64 + x];
    float p3 = p_s[(cg * 4 + 3) * 64 + x];
#pragma unroll
    for (int oo = 0; oo < 4; ++oo) {
      const float4 w4 = *(const float4*)&w_s[(og * 4 + oo) * 64 + cg * 4];
      acc[oo] = fmaf(w4.x, p0, fmaf(w4.y, p1, fmaf(w4.z, p2, fmaf(w4.w, p3, acc[oo]))));
    }
  }
#pragma unroll
  for (int oo = 0; oo < 4; ++oo) {
    int o = og * 4 + oo;
    qf[(size_t)(b * CC + o) * HWP + hw0 + x] = acc[oo];
    t_s[x * 68 + o] = f2bf(acc[oo] * K_QSCALE);
  }
  __syncthreads();
  {
    int pix = tid >> 4, c4 = tid & 15;
    ushort4 v = *(const ushort4*)&t_s[pix * 68 + c4 * 4];
    *(ushort4*)&qb[(size_t)(b * HWP + hw0 + pix) * CC + c4 * 4] = v;
  }
}

// ---------------------------------------------------------------------------
// Kernel 2 (fused): depthwise3x3(q)+bias -> LN -> GELU(fast erf) -> offset
// proj -> tanh -> coords -> bilinear-sample kv -> K/V projection.
// Grid B*H = 256 x 1024 thr: 64 px x 16 channel-groups of 4.  (r7-verified)
// ---------------------------------------------------------------------------
__global__ __launch_bounds__(1024) void k_off_sample(
    const float* __restrict__ q, const float* __restrict__ dw_w,
    const float* __restrict__ dw_b, const float* __restrict__ ln_w,
    const float* __restrict__ ln_b, const float* __restrict__ off_w,
    const float* __restrict__ kv,
    const float* __restrict__ wk, const float* __restrict__ bk,
    const float* __restrict__ wv, const float* __restrict__ bv,
    unsigned short* __restrict__ kb, unsigned short* __restrict__ vb) {
  __shared__ float wk_s[64 * 64];
  __shared__ float wv_s[64 * 64];
  __shared__ float xs_s[64 * 64];   // [c][n]
  __shared__ float red0[16][64];
  __shared__ float red1[16][64];

  int tid = threadIdx.x;
  int x = tid & 63;
  int cg = tid >> 6;                // 0..15
  int by = blockIdx.x;              // b*H + y
  int b = by >> 6;
  int y = by & 63;

#pragma unroll
  for (int i = 0; i < 4; ++i) {
    wk_s[i * 1024 + tid] = wk[i * 1024 + tid];
    wv_s[i * 1024 + tid] = wv[i * 1024 + tid];
  }

  // ---- phase 1: offsets ----
  float t[4];
#pragma unroll
  for (int i = 0; i < 4; ++i) {
    int c = cg * 4 + i;
    float acc = dw_b[c];
    const float* qc = q + (size_t)(b * CC + c) * HWP;
#pragma unroll
    for (int ky = 0; ky < 3; ++ky) {
      int yy = y + ky - 1;
      bool yok = (yy >= 0) && (yy < HH);
#pragma unroll
      for (int kx = 0; kx < 3; ++kx) {
        int xx = x + kx - 1;
        bool ok = yok && (xx >= 0) && (xx < WW);
        float v = ok ? qc[yy * WW + xx] : 0.f;
        acc = fmaf(dw_w[c * 9 + ky * 3 + kx], v, acc);
      }
    }
    t[i] = acc;
  }
  float s1 = 0.f, s2 = 0.f;
#pragma unroll
  for (int i = 0; i < 4; ++i) { s1 += t[i]; s2 += t[i] * t[i]; }
  red0[cg][x] = s1;
  red1[cg][x] = s2;
  __syncthreads();
  float mu = 0.f, ms = 0.f;
#pragma unroll
  for (int g = 0; g < 16; ++g) { mu += red0[g][x]; ms += red1[g][x]; }
  mu *= (1.f / 64.f); ms *= (1.f / 64.f);
  float rstd = rsqrtf(ms - mu * mu + K_EPS);

  float oy = 0.f, ox = 0.f;
#pragma unroll
  for (int i = 0; i < 4; ++i) {
    int c = cg * 4 + i;
    float g = (t[i] - mu) * rstd * ln_w[c] + ln_b[c];
    g = 0.5f * g * (1.f + erf_fast(g * 0.70710678118654752f));
    oy = fmaf(off_w[c], g, oy);
    ox = fmaf(off_w[CC + c], g, ox);
  }
  __syncthreads();
  red0[cg][x] = oy;
  red1[cg][x] = ox;
  __syncthreads();
  if (cg == 0) {
    float osy = 0.f, osx = 0.f;
#pragma unroll
    for (int g = 0; g < 16; ++g) { osy += red0[g][x]; osx += red1[g][x]; }
    osy = tanhf(osy) * (K_OFR / (HH - 1));
    osx = tanhf(osx) * (K_OFR / (WW - 1));
    float ry = (y + 0.5f) * (2.f / 63.f) - 1.f;
    float rx = (x + 0.5f) * (2.f / 63.f) - 1.f;
    red0[0][x] = (osx + rx + 1.f) * 0.5f * (WW - 1);   // gx
    red0[1][x] = (osy + ry + 1.f) * 0.5f * (HH - 1);   // gy
  }
  __syncthreads();

  // ---- phase 2: sample + K/V projection ----
  int n = x, og = cg;
  int n0 = y * 64;
  float gx = red0[0][n], gy = red0[1][n];
  float x0f = floorf(gx), y0f = floorf(gy);
  float wx = gx - x0f, wy = gy - y0f;
  int x0 = (int)x0f, y0 = (int)y0f;
  int x1 = x0 + 1, y1 = y0 + 1;
  float m00 = (x0 >= 0 && x0 < WW && y0 >= 0 && y0 < HH) ? 1.f : 0.f;
  float m01 = (x1 >= 0 && x1 < WW && y0 >= 0 && y0 < HH) ? 1.f : 0.f;
  float m10 = (x0 >= 0 && x0 < WW && y1 >= 0 && y1 < HH) ? 1.f : 0.f;
  float m11 = (x1 >= 0 && x1 < WW && y1 >= 0 && y1 < HH) ? 1.f : 0.f;
  int x0c = min(max(x0, 0), WW - 1), x1c = min(max(x1, 0), WW - 1);
  int y0c = min(max(y0, 0), HH - 1), y1c = min(max(y1, 0), HH - 1);
  int i00 = y0c * WW + x0c, i01 = y0c * WW + x1c;
  int i10 = y1c * WW + x0c, i11 = y1c * WW + x1c;
  float w00 = m00 * (1.f - wx) * (1.f - wy);
  float w01 = m01 * wx * (1.f - wy);
  float w10 = m10 * (1.f - wx) * wy;
  float w11 = m11 * wx * wy;

  const float* base = kv + (size_t)b * CC * HWP;
#pragma unroll
  for (int i = 0; i < 4; ++i) {
    int c = og * 4 + i;
    const float* pc = base + (size_t)c * HWP;
    xs_s[c * 64 + n] = w00 * pc[i00] + w01 * pc[i01] + w10 * pc[i10] + w11 * pc[i11];
  }
  __syncthreads();
  float ak[4], av[4];
#pragma unroll
  for (int oo = 0; oo < 4; ++oo) { ak[oo] = bk[og * 4 + oo]; av[oo] = bv[og * 4 + oo]; }
  for (int cg2 = 0; cg2 < 16; ++cg2) {
    float p0 = xs_s[(cg2 * 4 + 0) * 64 + n];
    float p1 = xs_s[(cg2 * 4 + 1) * 64 + n];
    float p2 = xs_s[(cg2 * 4 + 2) * 64 + n];
    float p3 = xs_s[(cg2 * 4 + 3) * 64 + n];
#pragma unroll
    for (int oo = 0; oo < 4; ++oo) {
      int o = og * 4 + oo;
      const float4 k4 = *(const float4*)&wk_s[o * 64 + cg2 * 4];
      const float4 v4 = *(const float4*)&wv_s[o * 64 + cg2 * 4];
      ak[oo] = fmaf(k4.x, p0, fmaf(k4.y, p1, fmaf(k4.z, p2, fmaf(k4.w, p3, ak[oo]))));
      av[oo] = fmaf(v4.x, p0, fmaf(v4.y, p1, fmaf(v4.z, p2, fmaf(v4.w, p3, av[oo]))));
    }
  }
  int2 kk;
  kk.x = pack2bf(ak[0], ak[1]);
  kk.y = pack2bf(ak[2], ak[3]);
  *(int2*)&kb[(size_t)(b * NPTS + n0 + n) * CC + og * 4] = kk;
#pragma unroll
  for (int oo = 0; oo < 4; ++oo) {
    int o = og * 4 + oo;
    vb[(size_t)(b * CC + o) * NPTS + n0 + n] = f2bf(av[oo]);
  }
}

// ---------------------------------------------------------------------------
// Kernel 3: bf16 MFMA flash attention, 128-query tiles, 512 thr = 8 waves.
// Wave w owns queries m0 + w*16..+15 (wave-private P, r7 structure).
// K/V staging shared by 8 waves; LDS 36.8 KB -> 4 blocks/CU = 32 waves/CU.
// Grid = 32 mtiles * (B*NS) blocks; mtile in high bits (XCD L2 locality).
// ---------------------------------------------------------------------------
__global__ __launch_bounds__(512) void k_attn(
    const unsigned short* __restrict__ qb, const unsigned short* __restrict__ kb,
    const unsigned short* __restrict__ vb, float* __restrict__ opart,
    float* __restrict__ dpart, int ns_shift) {
  __shared__ short qp_s[128 * LDP];  // Q tile (128 rows), P aliased per-wave
  __shared__ short k_s[64 * LDP];
  __shared__ short v_s[64 * LDP];

  int tid = threadIdx.x;
  int w = tid >> 6, lane = tid & 63, quad = lane >> 4, l16 = lane & 15;
  int blk = blockIdx.x;              // mtile * (BB<<ns_shift) + (b<<ns_shift) + ns
  int pair = blk & ((BB << ns_shift) - 1);
  int mtile = blk >> (2 + ns_shift);
  int ns = pair & ((1 << ns_shift) - 1);
  int b = pair >> ns_shift;
  int m0 = mtile * 128;

  const unsigned short* qbb = qb + (size_t)b * HWP * CC;
  const unsigned short* kbb = kb + (size_t)b * NPTS * CC;
  const unsigned short* vbb = vb + (size_t)b * CC * NPTS;

  // stage Q tile [128][c] (16 KB, 2 passes of 512 x 16B)
#pragma unroll
  for (int pass = 0; pass < 2; ++pass) {
    int idx = pass * 512 + tid;
    int row = idx >> 3, part = idx & 7;
    uint4 d = *(const uint4*)(qbb + (size_t)(m0 + row) * CC + part * 8);
    *(uint4*)&qp_s[row * LDP + part * 8] = d;
  }
  __syncthreads();
  // hoist loop-invariant Q a-frags (wave-private rows w*16..w*16+15)
  frag8 a_frag[2];
#pragma unroll
  for (int kc = 0; kc < 2; ++kc)
    a_frag[kc] = *(const frag8*)&qp_s[(w * 16 + l16) * LDP + kc * 32 + quad * 8];

  frag8 ones;
#pragma unroll
  for (int i = 0; i < 8; ++i) ones[i] = (short)0x3F80;   // bf16 1.0

  f32x4 o_acc[4];
  f32x4 d4;
  const f32x4 zz = {0.f, 0.f, 0.f, 0.f};
#pragma unroll
  for (int i = 0; i < 4; ++i) o_acc[i] = zz;
  d4 = zz;

  int niters = (NPTS / 64) >> ns_shift;
  int nbase = ns * niters * 64;
  for (int it = 0; it < niters; ++it) {
    int n0 = nbase + it * 64;
    __syncthreads();   // prev-iter k_s/v_s reads done
    {
      int row = tid >> 3, part = tid & 7;   // 512 thr cover 64 rows x 8 parts
      uint4 dk = *(const uint4*)(kbb + (size_t)(n0 + row) * CC + part * 8);
      uint4 dv = *(const uint4*)(vbb + (size_t)row * NPTS + n0 + part * 8);
      *(uint4*)&k_s[row * LDP + part * 8] = dk;
      *(uint4*)&v_s[row * LDP + part * 8] = dv;
    }
    __syncthreads();

    // GEMM1': S^T per-wave: A = K tiles, B = Q regs -> cols = own queries
    f32x4 sT[4];
#pragma unroll
    for (int t = 0; t < 4; ++t) {
      frag8 kf = *(const frag8*)&k_s[(t * 16 + l16) * LDP + quad * 8];
      sT[t] = __builtin_amdgcn_mfma_f32_16x16x32_bf16(kf, a_frag[0], zz, 0, 0, 0);
    }
#pragma unroll
    for (int t = 0; t < 4; ++t) {
      frag8 kf = *(const frag8*)&k_s[(t * 16 + l16) * LDP + 32 + quad * 8];
      sT[t] = __builtin_amdgcn_mfma_f32_16x16x32_bf16(kf, a_frag[1], sT[t], 0, 0, 0);
    }
    // exp2 -> packed bf16 P[m][n] (wave-private rows)
#pragma unroll
    for (int t = 0; t < 4; ++t) {
      int base_sh = (w * 16 + l16) * LDP + t * 16 + quad * 4;  // even
      *(int*)&qp_s[base_sh]     = pack2bf(EXP2F(sT[t][0]), EXP2F(sT[t][1]));
      *(int*)&qp_s[base_sh + 2] = pack2bf(EXP2F(sT[t][2]), EXP2F(sT[t][3]));
    }
    // GEMM2: O^T[c][m] += V[c][n] * P^T[n][m];  d += ones * P^T
#pragma unroll
    for (int kc = 0; kc < 2; ++kc) {
      frag8 bp = *(const frag8*)&qp_s[(w * 16 + l16) * LDP + kc * 32 + quad * 8];
      d4 = __builtin_amdgcn_mfma_f32_16x16x32_bf16(ones, bp, d4, 0, 0, 0);
#pragma unroll
      for (int ct = 0; ct < 4; ++ct) {
        frag8 av = *(const frag8*)&v_s[(ct * 16 + l16) * LDP + kc * 32 + quad * 8];
        o_acc[ct] = __builtin_amdgcn_mfma_f32_16x16x32_bf16(av, bp, o_acc[ct], 0, 0, 0);
      }
    }
  }

  // O^T lane layout: c = ct*16 + quad*4 + reg, m = w*16 + l16
  float* op = opart + (size_t)((ns * BB + b) * HWP + m0 + w * 16 + l16) * CC;
#pragma unroll
  for (int ct = 0; ct < 4; ++ct) {
    float4 o4;
    o4.x = o_acc[ct][0]; o4.y = o_acc[ct][1]; o4.z = o_acc[ct][2]; o4.w = o_acc[ct][3];
    *(float4*)&op[ct * 16 + quad * 4] = o4;
  }
  if (lane < 16)
    dpart[(ns * BB + b) * HWP + m0 + w * 16 + lane] = d4[0];
}

// ---------------------------------------------------------------------------
// Kernel 4: combine NS partials, normalize, project with wo (r7-verified).
// ---------------------------------------------------------------------------
__global__ __launch_bounds__(256) void k_out(
    const float* __restrict__ opart, const float* __restrict__ dpart,
    const float* __restrict__ wo, const float* __restrict__ bo,
    float* __restrict__ out, int NS) {
  __shared__ float wo_s[CC * CC];
  __shared__ float t_s[32 * 65];    // [m][c] padded
  int tid = threadIdx.x;
  int blk = blockIdx.x;             // b*128 + mt
  int b = blk >> 7, mt = blk & 127, m0 = mt * 32;
  for (int i = tid; i < CC * CC; i += 256) wo_s[i] = wo[i];

#pragma unroll
  for (int it = 0; it < 8; ++it) {
    int idx = it * 256 + tid;
    int m = idx >> 6, c = idx & 63;
    float o = 0.f, d = 0.f;
    for (int s = 0; s < NS; ++s) {
      o += opart[(size_t)((s * BB + b) * HWP + m0 + m) * CC + c];
      d += dpart[(s * BB + b) * HWP + m0 + m];
    }
    t_s[m * 65 + c] = o / d;
  }
  __syncthreads();
  int ml = tid & 31, og = tid >> 5;  // og 0..7
  for (int oo = 0; oo < 8; ++oo) {
    int o = og * 8 + oo;
    float acc = bo[o];
#pragma unroll
    for (int c = 0; c < 64; ++c) acc = fmaf(wo_s[o * CC + c], t_s[ml * 65 + c], acc);
    out[(size_t)(b * CC + o) * HWP + m0 + ml] = acc;
  }
}

// ---------------------------------------------------------------------------
extern "C" void kernel_launch(void* const* d_in, const int* in_sizes, int n_in,
                              void* d_out, int out_size, void* d_ws, size_t ws_size,
                              hipStream_t stream) {
  const float* prompt = (const float*)d_in[0];
  const float* kv     = (const float*)d_in[1];
  const float* wq     = (const float*)d_in[2];
  const float* bq     = (const float*)d_in[3];
  const float* wk     = (const float*)d_in[4];
  const float* bk     = (const float*)d_in[5];
  const float* wv     = (const float*)d_in[6];
  const float* bv     = (const float*)d_in[7];
  const float* wo     = (const float*)d_in[8];
  const float* bo     = (const float*)d_in[9];
  const float* dw_w   = (const float*)d_in[10];
  const float* dw_b   = (const float*)d_in[11];
  const float* ln_w   = (const float*)d_in[12];
  const float* ln_b   = (const float*)d_in[13];
  const float* off_w  = (const float*)d_in[14];
  float* out = (float*)d_out;
  float* ws  = (float*)d_ws;

  // NS gating on workspace size (deterministic per run — ws_size is fixed).
  auto need = [](int ns) {
    return (size_t)((size_t)ns * 1048576 + 3 * 524288 + (size_t)ns * 16384) * sizeof(float);
  };
  int NS, ns_shift;
  if      (ws_size >= need(8)) { NS = 8; ns_shift = 3; }
  else if (ws_size >= need(4)) { NS = 4; ns_shift = 2; }
  else                         { NS = 2; ns_shift = 1; }

  float* opart          = ws;                         // [NS][B][M][C], aliases qf
  float* qf             = ws;                         // [B][C][HW] (dead before k_attn)
  unsigned short* qb    = (unsigned short*)(ws + (size_t)NS * 1048576);
  unsigned short* kb    = (unsigned short*)(ws + (size_t)NS * 1048576 + 524288);
  unsigned short* vb    = (unsigned short*)(ws + (size_t)NS * 1048576 + 2 * 524288);
  float* dpart          = ws + (size_t)NS * 1048576 + 3 * 524288;

  hipLaunchKernelGGL(k_qproj, dim3(BB * 64), dim3(1024), 0, stream,
                     prompt, wq, bq, qf, qb);
  hipLaunchKernelGGL(k_off_sample, dim3(BB * HH), dim3(1024), 0, stream,
                     qf, dw_w, dw_b, ln_w, ln_b, off_w,
                     kv, wk, bk, wv, bv, kb, vb);
  hipLaunchKernelGGL(k_attn, dim3(32 * BB * NS), dim3(512), 0, stream,
                     qb, kb, vb, opart, dpart, ns_shift);
  hipLaunchKernelGGL(k_out, dim3(BB * 128), dim3(256), 0, stream,
                     opart, dpart, wo, bo, out, NS);
}